// Round 1
// baseline (2317.153 us; speedup 1.0000x reference)
//
#include <hip/hip_runtime.h>
#include <hip/hip_bf16.h>

#define NM 16
#define NS 16384
#define DIMV 512

// One 64-lane wave per sample. Each lane holds 8 elements (2x float4) of each
// of the 16 vectors -> v[16][8] in VGPRs. Classical Gram-Schmidt (matches the
// reference's einsum-all-then-subtract order). Wave-wide shfl_xor butterfly
// reductions, batched per outer step i so the i independent dot reductions
// pipeline (dependent chain ~32 rounds, not 136).
__global__ __launch_bounds__(256) void ortho_gs_kernel(const float* __restrict__ x,
                                                       float* __restrict__ out) {
    const int gtid = blockIdx.x * blockDim.x + threadIdx.x;
    const int s    = gtid >> 6;          // sample = global wave id
    const int lane = threadIdx.x & 63;
    if (s >= NS) return;

    float v[NM][8];

    // Load: for vector m, lanes read a contiguous 1KB chunk (float4 per lane),
    // twice (elements d = lane*4..lane*4+3 and 256+lane*4..+3).
    #pragma unroll
    for (int m = 0; m < NM; ++m) {
        const float4* p = (const float4*)(x + (size_t)m * (size_t)NS * DIMV
                                            + (size_t)s * DIMV);
        float4 a = p[lane];
        float4 b = p[64 + lane];
        v[m][0] = a.x; v[m][1] = a.y; v[m][2] = a.z; v[m][3] = a.w;
        v[m][4] = b.x; v[m][5] = b.y; v[m][6] = b.z; v[m][7] = b.w;
    }

    // Classical Gram-Schmidt, fully unrolled (compile-time register indexing).
    #pragma unroll
    for (int i = 0; i < NM; ++i) {
        float c[NM];
        // Partial dot products of v[i] against all previous basis vectors.
        #pragma unroll
        for (int j = 0; j < NM; ++j) {
            if (j < i) {
                float p = 0.f;
                #pragma unroll
                for (int e = 0; e < 8; ++e) p = fmaf(v[i][e], v[j][e], p);
                c[j] = p;
            }
        }
        // Batched butterfly reduction across the wave (independent per j).
        #pragma unroll
        for (int st = 1; st < 64; st <<= 1) {
            #pragma unroll
            for (int j = 0; j < NM; ++j) {
                if (j < i) c[j] += __shfl_xor(c[j], st, 64);
            }
        }
        // Subtract all projections (classical GS, like the reference).
        #pragma unroll
        for (int j = 0; j < NM; ++j) {
            if (j < i) {
                #pragma unroll
                for (int e = 0; e < 8; ++e) v[i][e] = fmaf(-c[j], v[j][e], v[i][e]);
            }
        }
        // Normalize.
        float n = 0.f;
        #pragma unroll
        for (int e = 0; e < 8; ++e) n = fmaf(v[i][e], v[i][e], n);
        #pragma unroll
        for (int st = 1; st < 64; st <<= 1) n += __shfl_xor(n, st, 64);
        const float inv = 1.0f / sqrtf(n);
        #pragma unroll
        for (int e = 0; e < 8; ++e) v[i][e] *= inv;
    }

    // Store in the same layout: out[k, s, d].
    #pragma unroll
    for (int m = 0; m < NM; ++m) {
        float4* p = (float4*)(out + (size_t)m * (size_t)NS * DIMV
                                  + (size_t)s * DIMV);
        p[lane]      = make_float4(v[m][0], v[m][1], v[m][2], v[m][3]);
        p[64 + lane] = make_float4(v[m][4], v[m][5], v[m][6], v[m][7]);
    }
}

extern "C" void kernel_launch(void* const* d_in, const int* in_sizes, int n_in,
                              void* d_out, int out_size, void* d_ws, size_t ws_size,
                              hipStream_t stream) {
    const float* x = (const float*)d_in[0];
    float* out = (float*)d_out;
    // One wave per sample: 16384 waves; 4 waves per 256-thread block.
    const int threads = 256;
    const int waves_per_block = threads / 64;
    const int blocks = (NS + waves_per_block - 1) / waves_per_block;
    ortho_gs_kernel<<<blocks, threads, 0, stream>>>(x, out);
}